// Round 4
// baseline (387.109 us; speedup 1.0000x reference)
//
#include <hip/hip_runtime.h>
#include <cstdint>

namespace {
constexpr int B = 8, C = 3, H = 1024, W = 1024;
constexpr int HO = 256, WO = 256, K2 = 9;
constexpr int HP = H + 2, WP = W + 2;

__device__ __forceinline__ int reflect_src(int p, int n) {
    // padded index p in [0, n+1] -> source index in [0, n-1] (numpy 'reflect')
    int s = p - 1;
    s = (s < 0) ? -s : s;
    s = (s >= n) ? (2 * n - 2 - s) : s;
    return s;
}

// min 4 waves/EU -> VGPR cap 128: enough to hold 9 taps' gather state (54)
// plus a 36-wide in-flight load batch per channel. 32-VGPR/8-wave build was
// latency-bound with ~5 outstanding gathers/wave.
__global__ __launch_bounds__(256, 4) void ds_kernel(
    const float* __restrict__ img,
    const float* __restrict__ kern,
    const float* __restrict__ offh,
    const float* __restrict__ offv,
    const float* __restrict__ ou_p,
    float* __restrict__ out) {
    // XCD-aware swizzle: XCD = blockIdx % 8 = batch; each XCD walks one image
    // contiguously in h so the input-row reuse window stays in its 4 MiB L2.
    const int b = blockIdx.x & 7;
    const int h = blockIdx.x >> 3;
    const int w = threadIdx.x;

    const float ou = ou_p[0];
    const float cy = (h + 0.5f) * 4.0f - 0.5f;
    const float cx = (w + 0.5f) * 4.0f - 0.5f;

    // ---- Phase 1: compute compressed gather state for all 9 taps ----
    int   i00[K2], dx[K2], dy[K2];
    float aw[K2], bw[K2], kv[K2];
    {
        size_t pbase = ((size_t)b * K2) * (size_t)(HO * WO) + (size_t)h * WO + w;
#pragma unroll
        for (int k = 0; k < K2; ++k) {
            size_t o = pbase + (size_t)(k * HO * WO);
            kv[k] = kern[o];
            float py = cy + (float)(k / 3) + offv[o] * ou;
            float px = cx + (float)(k % 3) + offh[o] * ou;

            float y0f = floorf(py), x0f = floorf(px);
            bw[k] = py - y0f;
            aw[k] = px - x0f;

            int y0 = (int)y0f, x0 = (int)x0f;
            y0 = min(max(y0, 0), HP - 1);
            x0 = min(max(x0, 0), WP - 1);
            int y1 = min(y0 + 1, HP - 1);
            int x1 = min(x0 + 1, WP - 1);

            int sy0 = reflect_src(y0, H), sy1 = reflect_src(y1, H);
            int sx0 = reflect_src(x0, W), sx1 = reflect_src(x1, W);

            i00[k] = sy0 * W + sx0;
            dx[k]  = sx1 - sx0;          // i01 - i00
            dy[k]  = (sy1 - sy0) * W;    // i10 - i00; i11 = i00 + dy + dx
        }
    }

    // ---- Phase 2: per channel, batch-issue all 36 corner gathers, then FMA ----
    float acc[C] = {};
    const float* __restrict__ icb = img + (size_t)b * (C * H * W);
#pragma unroll
    for (int c = 0; c < C; ++c) {
        const float* __restrict__ ic = icb + (size_t)c * (H * W);
        float v00[K2], v01[K2], v10[K2], v11[K2];
#pragma unroll
        for (int k = 0; k < K2; ++k) {
            int i0 = i00[k];
            v00[k] = ic[i0];
            v01[k] = ic[i0 + dx[k]];
            v10[k] = ic[i0 + dy[k]];
            v11[k] = ic[i0 + dy[k] + dx[k]];
        }
#pragma unroll
        for (int k = 0; k < K2; ++k) {
            float aa = aw[k], bb = bw[k];
            float top = v00[k] + aa * (v01[k] - v00[k]);
            float bot = v10[k] + aa * (v11[k] - v10[k]);
            acc[c] += kv[k] * (top + bb * (bot - top));
        }
    }

    size_t obase = ((size_t)b * C) * (size_t)(HO * WO) + (size_t)h * WO + w;
#pragma unroll
    for (int c = 0; c < C; ++c)
        out[obase + (size_t)c * (HO * WO)] = acc[c];
}
} // namespace

extern "C" void kernel_launch(void* const* d_in, const int* in_sizes, int n_in,
                              void* d_out, int out_size, void* d_ws, size_t ws_size,
                              hipStream_t stream) {
    const float* img  = (const float*)d_in[0];
    const float* kern = (const float*)d_in[1];
    const float* offh = (const float*)d_in[2];
    const float* offv = (const float*)d_in[3];
    const float* ou   = (const float*)d_in[4];
    float* out = (float*)d_out;

    dim3 block(256);
    dim3 grid(B * HO);   // 2048 blocks; one output row (b,h) each, XCD-swizzled
    hipLaunchKernelGGL(ds_kernel, grid, block, 0, stream,
                       img, kern, offh, offv, ou, out);
}

// Round 5
// 297.427 us; speedup vs baseline: 1.3015x; 1.3015x over previous
//
#include <hip/hip_runtime.h>
#include <cstdint>

namespace {
constexpr int B = 8, C = 3, H = 1024, W = 1024;
constexpr int HO = 256, WO = 256, K2 = 9;
constexpr int HP = H + 2, WP = W + 2;
constexpr int HW = H * W, HOWO = HO * WO;

__device__ __forceinline__ int reflect_src(int p, int n) {
    // padded index p in [0, n+1] -> source index in [0, n-1] (numpy 'reflect')
    int s = p - 1;
    s = (s < 0) ? -s : s;
    s = (s >= n) ? (2 * n - 2 - s) : s;
    return s;
}

// Software-pipelined gather loop. Peak live set ~57 VGPRs by design so the
// compiler's preferred 64-VGPR / 8-waves-per-SIMD point needs NO spills
// (round-4 lesson: a 36-wide monolithic batch spills at 64 VGPRs).
__global__ __launch_bounds__(256) void ds_kernel(
    const float* __restrict__ img,
    const float* __restrict__ kern,
    const float* __restrict__ offh,
    const float* __restrict__ offv,
    const float* __restrict__ ou_p,
    float* __restrict__ out) {
    // XCD swizzle: XCD = blockIdx % 8 = batch; each XCD walks one image in h
    // so the input-row reuse window stays in its private 4 MiB L2.
    const int b = blockIdx.x & 7;
    const int h = blockIdx.x >> 3;
    const int w = threadIdx.x;

    const float ou = ou_p[0];
    const float cy = (h + 0.5f) * 4.0f - 0.5f;
    const float cx = (w + 0.5f) * 4.0f - 0.5f;
    const float* __restrict__ img0 = img + (size_t)b * (C * HW);
    const float* __restrict__ img1 = img0 + HW;
    const float* __restrict__ img2 = img1 + HW;
    const size_t pb = ((size_t)b * K2) * (size_t)HOWO + (size_t)h * WO + w;

    // 2-slot rotating pipeline state
    float pk[2], pv[2], ph[2];      // raw params (prefetched 2 taps ahead)
    float aw[2], bw[2], kvs[2];     // processed tap state
    float v[2][12];                 // in-flight gather values (12 per tap)
    float acc0 = 0.f, acc1 = 0.f, acc2 = 0.f;

    auto pload = [&](int k, int s) {
        size_t o = pb + (size_t)(k * HOWO);
        pk[s] = kern[o];
        pv[s] = offv[o];
        ph[s] = offh[o];
    };
    auto prep_issue = [&](int k, int s) {
        kvs[s] = pk[s];  // snapshot before pload(k+2) reuses the slot
        float py = cy + (float)(k / 3) + pv[s] * ou;
        float px = cx + (float)(k % 3) + ph[s] * ou;
        float y0f = floorf(py), x0f = floorf(px);
        bw[s] = py - y0f;
        aw[s] = px - x0f;
        int y0 = min(max((int)y0f, 0), HP - 1);
        int x0 = min(max((int)x0f, 0), WP - 1);
        int y1 = min(y0 + 1, HP - 1);
        int x1 = min(x0 + 1, WP - 1);
        int sy0 = reflect_src(y0, H), sy1 = reflect_src(y1, H);
        int sx0 = reflect_src(x0, W), sx1 = reflect_src(x1, W);
        int i0 = sy0 * W + sx0;
        int i1 = sy0 * W + sx1;
        int i2 = sy1 * W + sx0;
        int i3 = sy1 * W + sx1;
        v[s][0] = img0[i0]; v[s][1] = img0[i1]; v[s][2]  = img0[i2]; v[s][3]  = img0[i3];
        v[s][4] = img1[i0]; v[s][5] = img1[i1]; v[s][6]  = img1[i2]; v[s][7]  = img1[i3];
        v[s][8] = img2[i0]; v[s][9] = img2[i1]; v[s][10] = img2[i2]; v[s][11] = img2[i3];
    };
    auto consume = [&](int s) {
        float a = aw[s], be = bw[s], kw = kvs[s];
        float t, u;
        t = v[s][0] + a * (v[s][1] - v[s][0]);
        u = v[s][2] + a * (v[s][3] - v[s][2]);
        acc0 += kw * (t + be * (u - t));
        t = v[s][4] + a * (v[s][5] - v[s][4]);
        u = v[s][6] + a * (v[s][7] - v[s][6]);
        acc1 += kw * (t + be * (u - t));
        t = v[s][8] + a * (v[s][9] - v[s][8]);
        u = v[s][10] + a * (v[s][11] - v[s][10]);
        acc2 += kw * (t + be * (u - t));
    };

    pload(0, 0);
    pload(1, 1);
    prep_issue(0, 0);
#pragma unroll
    for (int k = 0; k < K2; ++k) {
        const int s = k & 1, n = s ^ 1;
        if (k + 2 < K2) pload(k + 2, s);        // params 2 taps ahead
        if (k + 1 < K2) prep_issue(k + 1, n);   // gathers 1 tap ahead
        consume(s);
    }

    size_t obase = ((size_t)b * C) * (size_t)HOWO + (size_t)h * WO + w;
    out[obase] = acc0;
    out[obase + (size_t)HOWO] = acc1;
    out[obase + (size_t)(2 * HOWO)] = acc2;
}
} // namespace

extern "C" void kernel_launch(void* const* d_in, const int* in_sizes, int n_in,
                              void* d_out, int out_size, void* d_ws, size_t ws_size,
                              hipStream_t stream) {
    const float* img  = (const float*)d_in[0];
    const float* kern = (const float*)d_in[1];
    const float* offh = (const float*)d_in[2];
    const float* offv = (const float*)d_in[3];
    const float* ou   = (const float*)d_in[4];
    float* out = (float*)d_out;

    dim3 block(256);
    dim3 grid(B * HO);   // 2048 blocks; one output row (b,h) each, XCD-swizzled
    hipLaunchKernelGGL(ds_kernel, grid, block, 0, stream,
                       img, kern, offh, offv, ou, out);
}

// Round 6
// 287.558 us; speedup vs baseline: 1.3462x; 1.0343x over previous
//
#include <hip/hip_runtime.h>
#include <cstdint>

namespace {
constexpr int B = 8, C = 3, H = 1024, W = 1024;
constexpr int HO = 256, WO = 256, K2 = 9;
constexpr int HP = H + 2, WP = W + 2;
constexpr int HW = H * W, HOWO = HO * WO;
constexpr size_t WS_NEED = (size_t)B * HW * 4 * sizeof(float);  // 128 MiB NHWC4

__device__ __forceinline__ int reflect_src(int p, int n) {
    // padded index p in [0, n+1] -> source index in [0, n-1] (numpy 'reflect')
    int s = p - 1;
    s = (s < 0) ? -s : s;
    s = (s >= n) ? (2 * n - 2 - s) : s;
    return s;
}

// ---- Pass 1: repack (B,C,H,W) f32 -> (B,H,W,4) float4 in workspace ----
// Pure streaming: 3 coalesced dword reads + 1 coalesced 16B store per px.
__global__ __launch_bounds__(256) void relayout(
    const float* __restrict__ img, float4* __restrict__ dst) {
    int gid = blockIdx.x * 256 + threadIdx.x;   // one thread per pixel
    int b = gid >> 20;                           // HW = 1M px per image
    int p = gid & (HW - 1);
    const float* base = img + (size_t)b * (C * HW) + p;
    dst[(size_t)b * HW + p] = make_float4(base[0], base[HW], base[2 * HW], 0.f);
}

// ---- Pass 2: gather from NHWC4 — one dwordx4 per bilinear corner (3 ch) ----
// Round-5 lesson: the gather path is TA/L1 address-throughput bound, not
// latency bound; this cuts divergent gather instructions 108 -> 36 per thread.
__global__ __launch_bounds__(256) void ds_nhwc(
    const float4* __restrict__ img4,
    const float* __restrict__ kern,
    const float* __restrict__ offh,
    const float* __restrict__ offv,
    const float* __restrict__ ou_p,
    float* __restrict__ out) {
    // XCD swizzle: XCD = blockIdx % 8 = batch; each XCD walks one image in h
    // so the input-row reuse window stays in its private 4 MiB L2.
    const int b = blockIdx.x & 7;
    const int h = blockIdx.x >> 3;
    const int w = threadIdx.x;

    const float ou = ou_p[0];
    const float cy = (h + 0.5f) * 4.0f - 0.5f;
    const float cx = (w + 0.5f) * 4.0f - 0.5f;
    const float4* __restrict__ ic = img4 + (size_t)b * HW;
    const size_t pb = ((size_t)b * K2) * (size_t)HOWO + (size_t)h * WO + w;

    float acc0 = 0.f, acc1 = 0.f, acc2 = 0.f;

#pragma unroll
    for (int k = 0; k < K2; ++k) {
        size_t o = pb + (size_t)(k * HOWO);
        float kv = kern[o];
        float py = cy + (float)(k / 3) + offv[o] * ou;
        float px = cx + (float)(k % 3) + offh[o] * ou;

        float y0f = floorf(py), x0f = floorf(px);
        float bb = py - y0f;
        float aa = px - x0f;

        int y0 = min(max((int)y0f, 0), HP - 1);
        int x0 = min(max((int)x0f, 0), WP - 1);
        int y1 = min(y0 + 1, HP - 1);
        int x1 = min(x0 + 1, WP - 1);
        int sy0 = reflect_src(y0, H), sy1 = reflect_src(y1, H);
        int sx0 = reflect_src(x0, W), sx1 = reflect_src(x1, W);

        float4 v00 = ic[sy0 * W + sx0];
        float4 v01 = ic[sy0 * W + sx1];
        float4 v10 = ic[sy1 * W + sx0];
        float4 v11 = ic[sy1 * W + sx1];

        float tx_, tu_;
        tx_ = v00.x + aa * (v01.x - v00.x);
        tu_ = v10.x + aa * (v11.x - v10.x);
        acc0 += kv * (tx_ + bb * (tu_ - tx_));
        tx_ = v00.y + aa * (v01.y - v00.y);
        tu_ = v10.y + aa * (v11.y - v10.y);
        acc1 += kv * (tx_ + bb * (tu_ - tx_));
        tx_ = v00.z + aa * (v01.z - v00.z);
        tu_ = v10.z + aa * (v11.z - v10.z);
        acc2 += kv * (tx_ + bb * (tu_ - tx_));
    }

    size_t obase = ((size_t)b * C) * (size_t)HOWO + (size_t)h * WO + w;
    out[obase] = acc0;
    out[obase + (size_t)HOWO] = acc1;
    out[obase + (size_t)(2 * HOWO)] = acc2;
}

// ---- Fallback (round-5 path) if workspace is too small for NHWC4 ----
__global__ __launch_bounds__(256) void ds_chw(
    const float* __restrict__ img,
    const float* __restrict__ kern,
    const float* __restrict__ offh,
    const float* __restrict__ offv,
    const float* __restrict__ ou_p,
    float* __restrict__ out) {
    const int b = blockIdx.x & 7;
    const int h = blockIdx.x >> 3;
    const int w = threadIdx.x;

    const float ou = ou_p[0];
    const float cy = (h + 0.5f) * 4.0f - 0.5f;
    const float cx = (w + 0.5f) * 4.0f - 0.5f;
    const float* __restrict__ img0 = img + (size_t)b * (C * HW);
    const float* __restrict__ img1 = img0 + HW;
    const float* __restrict__ img2 = img1 + HW;
    const size_t pb = ((size_t)b * K2) * (size_t)HOWO + (size_t)h * WO + w;

    float acc0 = 0.f, acc1 = 0.f, acc2 = 0.f;
#pragma unroll
    for (int k = 0; k < K2; ++k) {
        size_t o = pb + (size_t)(k * HOWO);
        float kv = kern[o];
        float py = cy + (float)(k / 3) + offv[o] * ou;
        float px = cx + (float)(k % 3) + offh[o] * ou;
        float y0f = floorf(py), x0f = floorf(px);
        float bb = py - y0f;
        float aa = px - x0f;
        int y0 = min(max((int)y0f, 0), HP - 1);
        int x0 = min(max((int)x0f, 0), WP - 1);
        int y1 = min(y0 + 1, HP - 1);
        int x1 = min(x0 + 1, WP - 1);
        int sy0 = reflect_src(y0, H), sy1 = reflect_src(y1, H);
        int sx0 = reflect_src(x0, W), sx1 = reflect_src(x1, W);
        int i0 = sy0 * W + sx0, i1 = sy0 * W + sx1;
        int i2 = sy1 * W + sx0, i3 = sy1 * W + sx1;
        float t, u;
        t = img0[i0] + aa * (img0[i1] - img0[i0]);
        u = img0[i2] + aa * (img0[i3] - img0[i2]);
        acc0 += kv * (t + bb * (u - t));
        t = img1[i0] + aa * (img1[i1] - img1[i0]);
        u = img1[i2] + aa * (img1[i3] - img1[i2]);
        acc1 += kv * (t + bb * (u - t));
        t = img2[i0] + aa * (img2[i1] - img2[i0]);
        u = img2[i2] + aa * (img2[i3] - img2[i2]);
        acc2 += kv * (t + bb * (u - t));
    }
    size_t obase = ((size_t)b * C) * (size_t)HOWO + (size_t)h * WO + w;
    out[obase] = acc0;
    out[obase + (size_t)HOWO] = acc1;
    out[obase + (size_t)(2 * HOWO)] = acc2;
}
} // namespace

extern "C" void kernel_launch(void* const* d_in, const int* in_sizes, int n_in,
                              void* d_out, int out_size, void* d_ws, size_t ws_size,
                              hipStream_t stream) {
    const float* img  = (const float*)d_in[0];
    const float* kern = (const float*)d_in[1];
    const float* offh = (const float*)d_in[2];
    const float* offv = (const float*)d_in[3];
    const float* ou   = (const float*)d_in[4];
    float* out = (float*)d_out;

    if (ws_size >= WS_NEED) {
        float4* img4 = (float4*)d_ws;
        hipLaunchKernelGGL(relayout, dim3((B * HW) / 256), dim3(256), 0, stream,
                           img, img4);
        hipLaunchKernelGGL(ds_nhwc, dim3(B * HO), dim3(256), 0, stream,
                           img4, kern, offh, offv, ou, out);
    } else {
        hipLaunchKernelGGL(ds_chw, dim3(B * HO), dim3(256), 0, stream,
                           img, kern, offh, offv, ou, out);
    }
}